// Round 6
// baseline (213.125 us; speedup 1.0000x reference)
//
#include <hip/hip_runtime.h>

// B=16, H=W=64, C=80; tables (127,80) -> reference resize is a no-op.
// Output (B,N,N) fp32 = 1.074 GB: pure HBM write-stream, floor ~165 us.
//
// v5 = v3 with PLAIN stores (A/B vs nontemporal). nt was introduced
// confounded with the 16-token restructure; theory: nt bypasses L3
// write-burst absorption, costing up to ~39 us of overlap.
#define HH 64
#define WW 64
#define CC 80
#define NN (HH * WW)
#define G  16          // tokens per block (along ww)
#define RPW 79         // pw rows needed: ww0 .. ww0+78
#define SP  84         // padded LDS stride: 16B-aligned rows, 8 words/bank

typedef float vf4 __attribute__((ext_vector_type(4)));

__global__ __launch_bounds__(256) void relpos_fused_v5(
    const float* __restrict__ q,    // (B, N, C)
    const float* __restrict__ ph,   // (127, 80)
    const float* __restrict__ pw,   // (127, 80)
    float* __restrict__ out)        // (B, N, N)
{
    __shared__ float sh_q [G * CC];     // 5.0 KB
    __shared__ float sh_pw[RPW * SP];   // 25.9 KB
    __shared__ float sh_dh[G * HH];     // 4.0 KB
    __shared__ float sh_dw[G * WW];     // 4.0 KB   -> 39.9 KB, 4 blocks/CU

    const int blk = blockIdx.x;          // b*256 + hh*4 + s
    const int s   = blk & 3;
    const int hh  = (blk >> 2) & 63;
    const int b   = blk >> 8;
    const int ww0 = s * G;
    const int t   = threadIdx.x;

    // ---- Phase 1: stage q rows + pw slice into LDS (coalesced) ----
    const vf4* qin4 = reinterpret_cast<const vf4*>(
        q + ((size_t)b * NN + hh * 64 + ww0) * CC);
    vf4* shq4 = reinterpret_cast<vf4*>(sh_q);
    #pragma unroll
    for (int p = t; p < G * CC / 4; p += 256) shq4[p] = qin4[p];

    const vf4* pwsrc = reinterpret_cast<const vf4*>(pw + (size_t)ww0 * CC);
    vf4* shpw4 = reinterpret_cast<vf4*>(sh_pw);
    for (int p = t; p < RPW * (CC / 4); p += 256) {
        const int r  = p / 20;           // row (80 floats = 20 vf4)
        const int w4 = p % 20;
        shpw4[r * (SP / 4) + w4] = pwsrc[p];
    }
    __syncthreads();

    // ---- Phase 2: each thread computes 4 rh-dots + 4 rw-dots ----
    const int j = t & 63;
    const int w = t >> 6;
    const float* phrow = ph + (size_t)(hh + 63 - j) * CC;  // L1-resident gather

    float acch[4] = {0.f, 0.f, 0.f, 0.f};
    float accw[4] = {0.f, 0.f, 0.f, 0.f};
    for (int c = 0; c < CC; c += 4) {
        vf4 hv = *reinterpret_cast<const vf4*>(phrow + c);
        #pragma unroll
        for (int k = 0; k < 4; ++k) {
            const int g = w + 4 * k;
            vf4 qv = *reinterpret_cast<const vf4*>(&sh_q[g * CC + c]);
            vf4 wv = *reinterpret_cast<const vf4*>(
                &sh_pw[(g + 63 - j) * SP + c]);
            acch[k] += qv.x * hv.x + qv.y * hv.y + qv.z * hv.z + qv.w * hv.w;
            accw[k] += qv.x * wv.x + qv.y * wv.y + qv.z * wv.z + qv.w * wv.w;
        }
    }
    #pragma unroll
    for (int k = 0; k < 4; ++k) {
        const int g = w + 4 * k;
        sh_dh[g * HH + j] = acch[k];
        sh_dw[g * WW + j] = accw[k];
    }
    __syncthreads();

    // ---- Phase 3: 16 tokens x 16 KB contiguous PLAIN stores ----
    // out[m] = rh[m>>6] + rw[m&63]; float4 p: j = p>>4, i0 = 4*(p&15).
    const vf4* dw4 = reinterpret_cast<const vf4*>(sh_dw);
    vf4* out4 = reinterpret_cast<vf4*>(
        out + ((size_t)b * NN + hh * 64 + ww0) * NN);
    for (int g = 0; g < G; ++g) {
        #pragma unroll
        for (int it = 0; it < 4; ++it) {
            const int p  = it * 256 + t;
            const float rh = sh_dh[g * HH + (p >> 4)];   // 4-addr broadcast
            const vf4 wv = dw4[g * 16 + (p & 15)];       // 2-way (free)
            vf4 o;
            o.x = rh + wv.x; o.y = rh + wv.y;
            o.z = rh + wv.z; o.w = rh + wv.w;
            out4[g * 1024 + p] = o;
        }
    }
}

extern "C" void kernel_launch(void* const* d_in, const int* in_sizes, int n_in,
                              void* d_out, int out_size, void* d_ws, size_t ws_size,
                              hipStream_t stream) {
    const float* q  = (const float*)d_in[0];
    const float* ph = (const float*)d_in[1];
    const float* pw = (const float*)d_in[2];
    float* out = (float*)d_out;

    const int B = in_sizes[0] / (NN * CC);        // 16
    dim3 grid(B * HH * (WW / G));                  // 4096 blocks
    relpos_fused_v5<<<grid, 256, 0, stream>>>(q, ph, pw, out);
}

// Round 7
// 196.566 us; speedup vs baseline: 1.0842x; 1.0842x over previous
//
#include <hip/hip_runtime.h>

// B=16, H=W=64, C=80; tables (127,80) -> reference resize is a no-op.
// Output (B,N,N) fp32 = 1.074 GB: HBM write-stream problem, floor ~165 us.
//
// v6 = v3 phase1/2 + register-resident phase 3:
//  - accumulators stay in VGPRs; cross-lane rh/rw values fetched with wave
//    shuffles (ds_bpermute) batched per token, THEN 16 dependency-free nt
//    stores. Store issue no longer waits on LDS reads contending with other
//    blocks' phase-2 bursts.
//  - sh_dh/sh_dw deleted (LDS 39.9 -> 30.9 KB => 5 blocks/CU), 2nd barrier
//    and result ds_writes deleted.
#define HH 64
#define WW 64
#define CC 80
#define NN (HH * WW)
#define G  16          // tokens per block
#define RPW 79         // pw rows needed: ww0 .. ww0+78
#define SP  84         // padded LDS stride: 16B-aligned rows, 8 words/bank

typedef float vf4 __attribute__((ext_vector_type(4)));

__global__ __launch_bounds__(256, 5) void relpos_fused_v6(
    const float* __restrict__ q,    // (B, N, C)
    const float* __restrict__ ph,   // (127, 80)
    const float* __restrict__ pw,   // (127, 80)
    float* __restrict__ out)        // (B, N, N)
{
    __shared__ float sh_q [G * CC];     // 5.0 KB
    __shared__ float sh_pw[RPW * SP];   // 25.9 KB  -> 30.9 KB, 5 blocks/CU

    const int blk = blockIdx.x;          // b*256 + hh*4 + s
    const int s   = blk & 3;
    const int hh  = (blk >> 2) & 63;
    const int b   = blk >> 8;
    const int ww0 = s * G;
    const int t   = threadIdx.x;

    // ---- Phase 1: stage q rows + pw slice into LDS (coalesced) ----
    const vf4* qin4 = reinterpret_cast<const vf4*>(
        q + ((size_t)b * NN + hh * 64 + ww0) * CC);
    vf4* shq4 = reinterpret_cast<vf4*>(sh_q);
    #pragma unroll
    for (int p = t; p < G * CC / 4; p += 256) shq4[p] = qin4[p];

    const vf4* pwsrc = reinterpret_cast<const vf4*>(pw + (size_t)ww0 * CC);
    vf4* shpw4 = reinterpret_cast<vf4*>(sh_pw);
    for (int p = t; p < RPW * (CC / 4); p += 256) {
        const int r  = p / 20;           // row (80 floats = 20 vf4)
        const int w4 = p % 20;
        shpw4[r * (SP / 4) + w4] = pwsrc[p];
    }
    __syncthreads();

    // ---- Phase 2 (per wave): dots for tokens g = w + 4k ----
    // lane j: acch[k] = rh_g[j] = dot(q[g], ph[hh+63-j])
    //         accw[k] = rw_g[j] = dot(q[g], pw[ww0+g+63-j])
    const int j = t & 63;
    const int w = t >> 6;
    const float* phrow = ph + (size_t)(hh + 63 - j) * CC;  // L1-resident gather

    float acch[4] = {0.f, 0.f, 0.f, 0.f};
    float accw[4] = {0.f, 0.f, 0.f, 0.f};
    for (int c = 0; c < CC; c += 4) {
        vf4 hv = *reinterpret_cast<const vf4*>(phrow + c);
        #pragma unroll
        for (int k = 0; k < 4; ++k) {
            const int g = w + 4 * k;
            vf4 qv = *reinterpret_cast<const vf4*>(&sh_q[g * CC + c]);
            vf4 wv = *reinterpret_cast<const vf4*>(
                &sh_pw[(g + 63 - j) * SP + c]);
            acch[k] += qv.x * hv.x + qv.y * hv.y + qv.z * hv.z + qv.w * hv.w;
            accw[k] += qv.x * wv.x + qv.y * wv.y + qv.z * wv.z + qv.w * wv.w;
        }
    }

    // ---- Phase 3 (per wave): shuffle-to-regs, then stream nt stores ----
    // out elem m of token g: rh_g[m>>6] + rw_g[m&63].
    // vf4 p = it*64 + j: rh idx = it*4 + (j>>4); rw floats = 4*(j&15)+0..3.
    vf4* out4 = reinterpret_cast<vf4*>(
        out + ((size_t)b * NN + hh * 64 + ww0) * NN);
    const int rwlane = 4 * (j & 15);
    const int rhbase = j >> 4;
    #pragma unroll
    for (int k = 0; k < 4; ++k) {
        const int g = w + 4 * k;
        const float w0 = __shfl(accw[k], rwlane + 0);
        const float w1 = __shfl(accw[k], rwlane + 1);
        const float w2 = __shfl(accw[k], rwlane + 2);
        const float w3 = __shfl(accw[k], rwlane + 3);
        float rh[16];
        #pragma unroll
        for (int it = 0; it < 16; ++it)
            rh[it] = __shfl(acch[k], it * 4 + rhbase);
        #pragma unroll
        for (int it = 0; it < 16; ++it) {
            vf4 o;
            o.x = rh[it] + w0; o.y = rh[it] + w1;
            o.z = rh[it] + w2; o.w = rh[it] + w3;
            __builtin_nontemporal_store(o, &out4[g * 1024 + it * 64 + j]);
        }
    }
}

extern "C" void kernel_launch(void* const* d_in, const int* in_sizes, int n_in,
                              void* d_out, int out_size, void* d_ws, size_t ws_size,
                              hipStream_t stream) {
    const float* q  = (const float*)d_in[0];
    const float* ph = (const float*)d_in[1];
    const float* pw = (const float*)d_in[2];
    float* out = (float*)d_out;

    const int B = in_sizes[0] / (NN * CC);        // 16
    dim3 grid(B * HH * (WW / G));                  // 4096 blocks
    relpos_fused_v6<<<grid, 256, 0, stream>>>(q, ph, pw, out);
}